// Round 2
// baseline (424.046 us; speedup 1.0000x reference)
//
#include <hip/hip_runtime.h>

// PatientMeanEncoder: causal nonzero-mean pool over concat(timesteps, MLP(dem)).
// N=64, L=2048, C_IN=256, DEM=10, hidden 40 -> 20, C_OUT = 276.
//
// Round 1 was latency-bound (320 waves, 3% occupancy, 14% HBM BW).
// This version splits L into SEG=16 segments (two-pass segmented scan):
//   k1: per-segment (sum, nonzero-count) partials -> d_ws   (4096 blocks)
//   k2: prefix from partials + local scan + write            (4096+64 blocks)
// dem channels (>=256) are constant along l, so causal nonzero-mean == the
// constant itself; written directly with float4 stores.

#define NB 64
#define LL 2048
#define CIN 256
#define COUT 276
#define DEMD 10
#define H1 40
#define H2 20
#define SEG 16
#define LSEG (LL / SEG)   // 128

__global__ __launch_bounds__(64) void pme_partials(
    const float* __restrict__ ts,   // (N, L, 256)
    float2* __restrict__ part)      // (N*4, SEG, 64) {sum, cnt}
{
    const int idx  = blockIdx.x;
    const int seg  = idx & (SEG - 1);
    const int tile = (idx >> 4) & 3;
    const int n    = idx >> 6;
    const int lane = threadIdx.x;

    const float* tp = ts + ((size_t)n * LL + seg * LSEG) * CIN + tile * 64 + lane;

    float sum = 0.0f, cnt = 0.0f;
    constexpr int U = 32;
    for (int l0 = 0; l0 < LSEG; l0 += U) {
        float v[U];
#pragma unroll
        for (int u = 0; u < U; ++u)
            v[u] = tp[(size_t)(l0 + u) * CIN];
#pragma unroll
        for (int u = 0; u < U; ++u) {
            sum += v[u];
            cnt += (v[u] != 0.0f) ? 1.0f : 0.0f;
        }
    }
    part[(((size_t)n * 4 + tile) * SEG + seg) * 64 + lane] = make_float2(sum, cnt);
}

__global__ __launch_bounds__(64) void pme_scan(
    const float* __restrict__ ts,    // (N, L, 256)
    const float2* __restrict__ part, // (N*4, SEG, 64)
    const float* __restrict__ dem,   // (N, 10)
    const float* __restrict__ W1, const float* __restrict__ b1,
    const float* __restrict__ W2, const float* __restrict__ b2,
    float* __restrict__ out)         // (N, L, 276)
{
    const int bid  = blockIdx.x;
    const int lane = threadIdx.x;

    if (bid < NB * 4 * SEG) {
        // ---- segmented causal nonzero-mean scan ----
        const int seg  = bid & (SEG - 1);
        const int tile = (bid >> 4) & 3;
        const int n    = bid >> 6;

        // exclusive prefix over preceding segments (small, L2/L3-hit)
        float acc = 0.0f, cnt = 0.0f;
        const float2* pp = part + (((size_t)n * 4 + tile) * SEG) * 64 + lane;
        for (int s = 0; s < seg; ++s) {
            float2 v = pp[(size_t)s * 64];
            acc += v.x;
            cnt += v.y;
        }

        const int c = tile * 64 + lane;
        const float* tp = ts  + ((size_t)n * LL + seg * LSEG) * CIN  + c;
        float*       op = out + ((size_t)n * LL + seg * LSEG) * COUT + c;

        constexpr int U = 32;
        for (int l0 = 0; l0 < LSEG; l0 += U) {
            float v[U];
#pragma unroll
            for (int u = 0; u < U; ++u)
                v[u] = tp[(size_t)(l0 + u) * CIN];
#pragma unroll
            for (int u = 0; u < U; ++u) {
                acc += v[u];
                cnt += (v[u] != 0.0f) ? 1.0f : 0.0f;
                float p = acc * __builtin_amdgcn_rcpf(fmaxf(cnt, 1.0f));
                op[(size_t)(l0 + u) * COUT] = fmaxf(p, 0.0f);
            }
        }
    } else {
        // ---- dem MLP + broadcast (channels 256..275, constant along l) ----
        const int n = bid - NB * 4 * SEG;
        const float* dn = dem + n * DEMD;

        // every lane computes the full 20-wide embedding (tiny, redundant)
        float h[H1];
#pragma unroll
        for (int k = 0; k < H1; ++k) {
            float hk = b1[k];
#pragma unroll
            for (int i = 0; i < DEMD; ++i)
                hk += dn[i] * W1[i * H1 + k];
            h[k] = fmaxf(hk, 0.0f);
        }
        float e[H2];
#pragma unroll
        for (int j = 0; j < H2; ++j) {
            float o = b2[j];
#pragma unroll
            for (int k = 0; k < H1; ++k)
                o += h[k] * W2[k * H2 + j];
            e[j] = fmaxf(o, 0.0f);
        }
        float4 e4[5];
#pragma unroll
        for (int q = 0; q < 5; ++q)
            e4[q] = make_float4(e[q * 4], e[q * 4 + 1], e[q * 4 + 2], e[q * 4 + 3]);

        // lane covers l = lane, lane+64, ...; 5 float4 stores per row
        for (int l = lane; l < LL; l += 64) {
            float4* op = (float4*)(out + ((size_t)n * LL + l) * COUT + CIN);
#pragma unroll
            for (int q = 0; q < 5; ++q)
                op[q] = e4[q];
        }
    }
}

extern "C" void kernel_launch(void* const* d_in, const int* in_sizes, int n_in,
                              void* d_out, int out_size, void* d_ws, size_t ws_size,
                              hipStream_t stream) {
    const float* ts  = (const float*)d_in[0];
    const float* dem = (const float*)d_in[1];
    const float* W1  = (const float*)d_in[2];
    const float* b1  = (const float*)d_in[3];
    const float* W2  = (const float*)d_in[4];
    const float* b2  = (const float*)d_in[5];
    float* out   = (float*)d_out;
    float2* part = (float2*)d_ws;   // 64*4*16*64 float2 = 2 MB

    pme_partials<<<NB * 4 * SEG, 64, 0, stream>>>(ts, part);
    pme_scan<<<NB * 4 * SEG + NB, 64, 0, stream>>>(ts, part, dem, W1, b1, W2, b2, out);
}

// Round 3
// 402.432 us; speedup vs baseline: 1.0537x; 1.0537x over previous
//
#include <hip/hip_runtime.h>

// PatientMeanEncoder: causal nonzero-mean pool over concat(timesteps, MLP(dem)).
// N=64, L=2048, C_IN=256, DEM=10, hidden 40 -> 20, C_OUT = 276.
//
// R2 post-mortem: both R1/R2 inner loops serialized at ~200 cyc/step —
// dword-granular accesses + stores convoying the vmcnt queue ahead of the
// next load batch. R3: float4 per lane (one wave = all 256 channels/row),
// explicit double-buffered prefetch so the next batch's loads are issued
// BEFORE this batch's stores (wait lands at vmcnt(8), never drains stores).
//
//   k1: per-segment (sum, nonzero-count) partials -> d_ws, + dem broadcast
//   k2: prefix from partials + local scan + float4 stores
//
// dem channels (>=256) are constant along l; causal nonzero-mean == the
// constant itself (v>0: (l+1)v/(l+1)=v; v==0: 0/max(0,1)=0).

#define NB 64
#define LL 2048
#define CIN 256
#define COUT 276
#define DEMD 10
#define H1 40
#define H2 20
#define SEG 32
#define LSEG (LL / SEG)     // 64 rows per segment
#define UB 8                // rows per prefetch batch (8 KB in flight / wave)
#define NBATCH (LSEG / UB)  // 8

// ---------------- kernel 1: segment partials + dem broadcast ----------------
__global__ __launch_bounds__(256) void pme_partials(
    const float* __restrict__ ts,   // (N, L, 256)
    float* __restrict__ part,       // (N, SEG, 256) x float2 {sum, cnt}
    const float* __restrict__ dem,  // (N, 10)
    const float* __restrict__ W1, const float* __restrict__ b1,
    const float* __restrict__ W2, const float* __restrict__ b2,
    float* __restrict__ out)        // (N, L, 276) — dem channels only
{
    const int tid  = threadIdx.x;
    const int w    = tid >> 6;      // wave in block
    const int lane = tid & 63;
    const int b    = blockIdx.x;

    if (b < (NB * SEG) / 4) {
        // one wave per (n, seg); lane covers channels 4*lane..4*lane+3
        const int unit = b * 4 + w;
        const int seg  = unit & (SEG - 1);
        const int n    = unit >> 5;

        const float4* tp = (const float4*)(ts + ((size_t)n * LL + seg * LSEG) * CIN) + lane;

        float4 sum = make_float4(0.f, 0.f, 0.f, 0.f);
        float4 cnt = make_float4(0.f, 0.f, 0.f, 0.f);

        float4 v[2][UB];
#pragma unroll
        for (int u = 0; u < UB; ++u)
            v[0][u] = tp[(size_t)u * (CIN / 4)];

        for (int bb = 0; bb < NBATCH; ++bb) {
            const int cur = bb & 1;
            if (bb + 1 < NBATCH) {
#pragma unroll
                for (int u = 0; u < UB; ++u)
                    v[cur ^ 1][u] = tp[(size_t)((bb + 1) * UB + u) * (CIN / 4)];
            }
#pragma unroll
            for (int u = 0; u < UB; ++u) {
                float4 x = v[cur][u];
                sum.x += x.x; cnt.x += (x.x != 0.f) ? 1.f : 0.f;
                sum.y += x.y; cnt.y += (x.y != 0.f) ? 1.f : 0.f;
                sum.z += x.z; cnt.z += (x.z != 0.f) ? 1.f : 0.f;
                sum.w += x.w; cnt.w += (x.w != 0.f) ? 1.f : 0.f;
            }
        }

        float4* pp = (float4*)(part + (((size_t)n * SEG + seg) * 256 + lane * 4) * 2);
        pp[0] = make_float4(sum.x, cnt.x, sum.y, cnt.y);
        pp[1] = make_float4(sum.z, cnt.z, sum.w, cnt.w);
    } else {
        // dem MLP + broadcast: one wave per n
        const int n = (b - (NB * SEG) / 4) * 4 + w;
        const float* dn = dem + n * DEMD;

        float h[H1];
#pragma unroll
        for (int k = 0; k < H1; ++k) {
            float hk = b1[k];
#pragma unroll
            for (int i = 0; i < DEMD; ++i)
                hk += dn[i] * W1[i * H1 + k];
            h[k] = fmaxf(hk, 0.f);
        }
        float e[H2];
#pragma unroll
        for (int j = 0; j < H2; ++j) {
            float o = b2[j];
#pragma unroll
            for (int k = 0; k < H1; ++k)
                o += h[k] * W2[k * H2 + j];
            e[j] = fmaxf(o, 0.f);
        }
        float4 e4[5];
#pragma unroll
        for (int q = 0; q < 5; ++q)
            e4[q] = make_float4(e[q * 4], e[q * 4 + 1], e[q * 4 + 2], e[q * 4 + 3]);

        // lane covers rows l = lane, lane+64, ... (32 rows); 5 float4/row
        for (int l = lane; l < LL; l += 64) {
            float4* op = (float4*)(out + ((size_t)n * LL + l) * COUT + CIN);
#pragma unroll
            for (int q = 0; q < 5; ++q)
                op[q] = e4[q];
        }
    }
}

// ---------------- kernel 2: prefix + local scan + write ----------------
__global__ __launch_bounds__(256) void pme_scan(
    const float* __restrict__ ts,   // (N, L, 256)
    const float* __restrict__ part, // (N, SEG, 256) x float2
    float* __restrict__ out)        // (N, L, 276)
{
    const int tid  = threadIdx.x;
    const int w    = tid >> 6;
    const int lane = tid & 63;

    const int unit = blockIdx.x * 4 + w;
    const int seg  = unit & (SEG - 1);
    const int n    = unit >> 5;

    // exclusive prefix over preceding segments (small, L2-hit)
    float4 acc = make_float4(0.f, 0.f, 0.f, 0.f);
    float4 cnt = make_float4(0.f, 0.f, 0.f, 0.f);
    const float4* pp = (const float4*)part + (size_t)n * SEG * 128 + lane * 2;
    for (int s = 0; s < seg; ++s) {
        float4 a  = pp[(size_t)s * 128];
        float4 bq = pp[(size_t)s * 128 + 1];
        acc.x += a.x;  cnt.x += a.y;
        acc.y += a.z;  cnt.y += a.w;
        acc.z += bq.x; cnt.z += bq.y;
        acc.w += bq.z; cnt.w += bq.w;
    }

    const float4* tp = (const float4*)(ts + ((size_t)n * LL + seg * LSEG) * CIN) + lane;
    float* op = out + ((size_t)n * LL + seg * LSEG) * COUT + lane * 4;

    float4 v[2][UB];
#pragma unroll
    for (int u = 0; u < UB; ++u)
        v[0][u] = tp[(size_t)u * (CIN / 4)];

    for (int bb = 0; bb < NBATCH; ++bb) {
        const int cur = bb & 1;
        // prefetch next batch BEFORE this batch's stores -> waits never drain stores
        if (bb + 1 < NBATCH) {
#pragma unroll
            for (int u = 0; u < UB; ++u)
                v[cur ^ 1][u] = tp[(size_t)((bb + 1) * UB + u) * (CIN / 4)];
        }
#pragma unroll
        for (int u = 0; u < UB; ++u) {
            float4 x = v[cur][u];
            float4 r;
            acc.x += x.x; cnt.x += (x.x != 0.f) ? 1.f : 0.f;
            acc.y += x.y; cnt.y += (x.y != 0.f) ? 1.f : 0.f;
            acc.z += x.z; cnt.z += (x.z != 0.f) ? 1.f : 0.f;
            acc.w += x.w; cnt.w += (x.w != 0.f) ? 1.f : 0.f;
            r.x = fmaxf(acc.x * __builtin_amdgcn_rcpf(fmaxf(cnt.x, 1.f)), 0.f);
            r.y = fmaxf(acc.y * __builtin_amdgcn_rcpf(fmaxf(cnt.y, 1.f)), 0.f);
            r.z = fmaxf(acc.z * __builtin_amdgcn_rcpf(fmaxf(cnt.z, 1.f)), 0.f);
            r.w = fmaxf(acc.w * __builtin_amdgcn_rcpf(fmaxf(cnt.w, 1.f)), 0.f);
            *(float4*)(op + (size_t)(bb * UB + u) * COUT) = r;
        }
    }
}

extern "C" void kernel_launch(void* const* d_in, const int* in_sizes, int n_in,
                              void* d_out, int out_size, void* d_ws, size_t ws_size,
                              hipStream_t stream) {
    const float* ts  = (const float*)d_in[0];
    const float* dem = (const float*)d_in[1];
    const float* W1  = (const float*)d_in[2];
    const float* b1  = (const float*)d_in[3];
    const float* W2  = (const float*)d_in[4];
    const float* b2  = (const float*)d_in[5];
    float* out  = (float*)d_out;
    float* part = (float*)d_ws;   // 64*32*256 float2 = 4 MB

    pme_partials<<<(NB * SEG) / 4 + NB / 4, 256, 0, stream>>>(ts, part, dem, W1, b1, W2, b2, out);
    pme_scan<<<(NB * SEG) / 4, 256, 0, stream>>>(ts, part, out);
}

// Round 4
// 337.307 us; speedup vs baseline: 1.2572x; 1.1931x over previous
//
#include <hip/hip_runtime.h>

// PatientMeanEncoder: causal nonzero-mean pool over concat(timesteps, MLP(dem)).
// N=64, L=2048, C_IN=256, DEM=10, hidden 40 -> 20, C_OUT = 276.
//
// R3 post-mortem: the ~110 us cost in EVERY round was the dem-broadcast
// scatter (64 waves, each store instr hitting 64 distinct lines at stride
// 1104 B -> 655K partial-line 16B writes, TCP serialization + L2 RMW).
// The scan phases were ~45 us (k1) and ~60 us (k2).
//
// R4: kill the scatter. Fuse dem channels into pme_scan's row writes:
// the scan wave writes bytes [0,1024) of each row coalesced; lanes 0-4 add
// one float4 store covering [1024,1104). Every line is fully written by
// temporally-close waves -> full-line writes, no RMW. Each scan wave
// recomputes the tiny dem MLP redundantly (wave-uniform L1-broadcast loads,
// hidden under memory latency). k1 is pure segment partials.
//
// dem channels are constant along l, so causal nonzero-mean == the constant
// itself (v>0: (l+1)v/(l+1)=v; v==0: 0/max(0,1)=0).

#define NB 64
#define LL 2048
#define CIN 256
#define COUT 276
#define DEMD 10
#define H1 40
#define H2 20
#define SEG 32
#define LSEG (LL / SEG)     // 64 rows per segment
#define UB 8                // rows per prefetch batch (8 KB in flight / wave)
#define NBATCH (LSEG / UB)  // 8

// ---------------- kernel 1: segment partials only ----------------
__global__ __launch_bounds__(256) void pme_partials(
    const float* __restrict__ ts,   // (N, L, 256)
    float* __restrict__ part)       // (N, SEG, 256) x float2 {sum, cnt}
{
    const int tid  = threadIdx.x;
    const int w    = tid >> 6;      // wave in block
    const int lane = tid & 63;

    const int unit = blockIdx.x * 4 + w;   // (n, seg); 4 segs of same n per block
    const int seg  = unit & (SEG - 1);
    const int n    = unit >> 5;

    const float4* tp = (const float4*)(ts + ((size_t)n * LL + seg * LSEG) * CIN) + lane;

    float4 sum = make_float4(0.f, 0.f, 0.f, 0.f);
    float4 cnt = make_float4(0.f, 0.f, 0.f, 0.f);

    float4 v[2][UB];
#pragma unroll
    for (int u = 0; u < UB; ++u)
        v[0][u] = tp[(size_t)u * (CIN / 4)];

    for (int bb = 0; bb < NBATCH; ++bb) {
        const int cur = bb & 1;
        if (bb + 1 < NBATCH) {
#pragma unroll
            for (int u = 0; u < UB; ++u)
                v[cur ^ 1][u] = tp[(size_t)((bb + 1) * UB + u) * (CIN / 4)];
        }
#pragma unroll
        for (int u = 0; u < UB; ++u) {
            float4 x = v[cur][u];
            sum.x += x.x; cnt.x += (x.x != 0.f) ? 1.f : 0.f;
            sum.y += x.y; cnt.y += (x.y != 0.f) ? 1.f : 0.f;
            sum.z += x.z; cnt.z += (x.z != 0.f) ? 1.f : 0.f;
            sum.w += x.w; cnt.w += (x.w != 0.f) ? 1.f : 0.f;
        }
    }

    float4* pp = (float4*)(part + (((size_t)n * SEG + seg) * 256 + lane * 4) * 2);
    pp[0] = make_float4(sum.x, cnt.x, sum.y, cnt.y);
    pp[1] = make_float4(sum.z, cnt.z, sum.w, cnt.w);
}

// ------------- kernel 2: prefix + local scan + fused dem write -------------
__global__ __launch_bounds__(256) void pme_scan(
    const float* __restrict__ ts,   // (N, L, 256)
    const float* __restrict__ part, // (N, SEG, 256) x float2
    const float* __restrict__ dem,  // (N, 10)
    const float* __restrict__ W1, const float* __restrict__ b1,
    const float* __restrict__ W2, const float* __restrict__ b2,
    float* __restrict__ out)        // (N, L, 276)
{
    const int tid  = threadIdx.x;
    const int w    = tid >> 6;
    const int lane = tid & 63;

    const int unit = blockIdx.x * 4 + w;
    const int seg  = unit & (SEG - 1);
    const int n    = unit >> 5;

    // ---- dem MLP (wave-uniform, redundant per wave; L1-broadcast loads) ----
    const float* dn = dem + n * DEMD;
    float h[H1];
#pragma unroll
    for (int k = 0; k < H1; ++k) {
        float hk = b1[k];
#pragma unroll
        for (int i = 0; i < DEMD; ++i)
            hk += dn[i] * W1[i * H1 + k];
        h[k] = fmaxf(hk, 0.f);
    }
    // this lane's quad of the 20-wide embedding (lanes 0..4 used for the store)
    float4 e4q = make_float4(0.f, 0.f, 0.f, 0.f);
    {
        const int q = (lane < 5) ? lane : 0;
        float e0 = b2[q * 4 + 0], e1 = b2[q * 4 + 1], e2 = b2[q * 4 + 2], e3 = b2[q * 4 + 3];
#pragma unroll
        for (int k = 0; k < H1; ++k) {
            e0 += h[k] * W2[k * H2 + q * 4 + 0];
            e1 += h[k] * W2[k * H2 + q * 4 + 1];
            e2 += h[k] * W2[k * H2 + q * 4 + 2];
            e3 += h[k] * W2[k * H2 + q * 4 + 3];
        }
        e4q = make_float4(fmaxf(e0, 0.f), fmaxf(e1, 0.f), fmaxf(e2, 0.f), fmaxf(e3, 0.f));
    }

    // ---- exclusive prefix over preceding segments (small, L2-hit) ----
    float4 acc = make_float4(0.f, 0.f, 0.f, 0.f);
    float4 cnt = make_float4(0.f, 0.f, 0.f, 0.f);
    const float4* pp = (const float4*)part + (size_t)n * SEG * 128 + lane * 2;
    for (int s = 0; s < seg; ++s) {
        float4 a  = pp[(size_t)s * 128];
        float4 bq = pp[(size_t)s * 128 + 1];
        acc.x += a.x;  cnt.x += a.y;
        acc.y += a.z;  cnt.y += a.w;
        acc.z += bq.x; cnt.z += bq.y;
        acc.w += bq.z; cnt.w += bq.w;
    }

    const float4* tp = (const float4*)(ts + ((size_t)n * LL + seg * LSEG) * CIN) + lane;
    float* oprow = out + ((size_t)n * LL + seg * LSEG) * COUT;

    float4 v[2][UB];
#pragma unroll
    for (int u = 0; u < UB; ++u)
        v[0][u] = tp[(size_t)u * (CIN / 4)];

    for (int bb = 0; bb < NBATCH; ++bb) {
        const int cur = bb & 1;
        // prefetch next batch BEFORE this batch's stores
        if (bb + 1 < NBATCH) {
#pragma unroll
            for (int u = 0; u < UB; ++u)
                v[cur ^ 1][u] = tp[(size_t)((bb + 1) * UB + u) * (CIN / 4)];
        }
#pragma unroll
        for (int u = 0; u < UB; ++u) {
            float4 x = v[cur][u];
            float4 r;
            acc.x += x.x; cnt.x += (x.x != 0.f) ? 1.f : 0.f;
            acc.y += x.y; cnt.y += (x.y != 0.f) ? 1.f : 0.f;
            acc.z += x.z; cnt.z += (x.z != 0.f) ? 1.f : 0.f;
            acc.w += x.w; cnt.w += (x.w != 0.f) ? 1.f : 0.f;
            r.x = fmaxf(acc.x * __builtin_amdgcn_rcpf(fmaxf(cnt.x, 1.f)), 0.f);
            r.y = fmaxf(acc.y * __builtin_amdgcn_rcpf(fmaxf(cnt.y, 1.f)), 0.f);
            r.z = fmaxf(acc.z * __builtin_amdgcn_rcpf(fmaxf(cnt.z, 1.f)), 0.f);
            r.w = fmaxf(acc.w * __builtin_amdgcn_rcpf(fmaxf(cnt.w, 1.f)), 0.f);
            float* rowp = oprow + (size_t)(bb * UB + u) * COUT;
            *(float4*)(rowp + lane * 4) = r;          // channels 0..255, coalesced
            if (lane < 5)
                *(float4*)(rowp + CIN + lane * 4) = e4q;  // channels 256..275
        }
    }
}

extern "C" void kernel_launch(void* const* d_in, const int* in_sizes, int n_in,
                              void* d_out, int out_size, void* d_ws, size_t ws_size,
                              hipStream_t stream) {
    const float* ts  = (const float*)d_in[0];
    const float* dem = (const float*)d_in[1];
    const float* W1  = (const float*)d_in[2];
    const float* b1  = (const float*)d_in[3];
    const float* W2  = (const float*)d_in[4];
    const float* b2  = (const float*)d_in[5];
    float* out  = (float*)d_out;
    float* part = (float*)d_ws;   // 64*32*256 float2 = 4 MB

    pme_partials<<<(NB * SEG) / 4, 256, 0, stream>>>(ts, part);
    pme_scan<<<(NB * SEG) / 4, 256, 0, stream>>>(ts, part, dem, W1, b1, W2, b2, out);
}

// Round 5
// 298.364 us; speedup vs baseline: 1.4212x; 1.1305x over previous
//
#include <hip/hip_runtime.h>

// PatientMeanEncoder: causal nonzero-mean pool over concat(timesteps, MLP(dem)).
// N=64, L=2048, C_IN=256, DEM=10, hidden 40 -> 20, C_OUT = 276.
//
// R4 post-mortem: dem-scatter fix confirmed (112us k2 + ~40us k1). k2 still
// latency-limited: 8 waves/CU (VGPR budget allows 16), long serial prefix
// prologue, and streaming output stores evicting the input from L2/L3.
// R5: SEG=64 (16 waves/CU), a tiny pme_prefix kernel that turns partials
// into exclusive prefixes (k2 prologue = one 32B read), and nontemporal
// output stores to keep the input L3-resident for k2's re-read.
//
// dem channels are constant along l, so causal nonzero-mean == the constant
// itself (v>0: (l+1)v/(l+1)=v; v==0: 0/max(0,1)=0).

#define NB 64
#define LL 2048
#define CIN 256
#define COUT 276
#define DEMD 10
#define H1 40
#define H2 20
#define SEG 64
#define LSEG (LL / SEG)     // 32 rows per segment
#define UB 8                // rows per prefetch batch (8 KB in flight / wave)
#define NBATCH (LSEG / UB)  // 4

typedef float vfloat4 __attribute__((ext_vector_type(4)));

static __device__ __forceinline__ void nt_store4(float* p, float4 v) {
    vfloat4 t = {v.x, v.y, v.z, v.w};
    __builtin_nontemporal_store(t, (vfloat4*)p);
}

// ---------------- kernel 1: segment partials ----------------
__global__ __launch_bounds__(256) void pme_partials(
    const float* __restrict__ ts,   // (N, L, 256)
    float* __restrict__ part)       // (N, SEG, 256) x {sum, cnt}
{
    const int tid  = threadIdx.x;
    const int w    = tid >> 6;
    const int lane = tid & 63;

    const int unit = blockIdx.x * 4 + w;   // (n, seg)
    const int seg  = unit & (SEG - 1);
    const int n    = unit >> 6;

    const float4* tp = (const float4*)(ts + ((size_t)n * LL + seg * LSEG) * CIN) + lane;

    float4 sum = make_float4(0.f, 0.f, 0.f, 0.f);
    float4 cnt = make_float4(0.f, 0.f, 0.f, 0.f);

    float4 v[2][UB];
#pragma unroll
    for (int u = 0; u < UB; ++u)
        v[0][u] = tp[(size_t)u * (CIN / 4)];

    for (int bb = 0; bb < NBATCH; ++bb) {
        const int cur = bb & 1;
        if (bb + 1 < NBATCH) {
#pragma unroll
            for (int u = 0; u < UB; ++u)
                v[cur ^ 1][u] = tp[(size_t)((bb + 1) * UB + u) * (CIN / 4)];
        }
#pragma unroll
        for (int u = 0; u < UB; ++u) {
            float4 x = v[cur][u];
            sum.x += x.x; cnt.x += (x.x != 0.f) ? 1.f : 0.f;
            sum.y += x.y; cnt.y += (x.y != 0.f) ? 1.f : 0.f;
            sum.z += x.z; cnt.z += (x.z != 0.f) ? 1.f : 0.f;
            sum.w += x.w; cnt.w += (x.w != 0.f) ? 1.f : 0.f;
        }
    }

    float4* pp = (float4*)part + ((size_t)n * SEG + seg) * 128 + lane * 2;
    pp[0] = make_float4(sum.x, cnt.x, sum.y, cnt.y);
    pp[1] = make_float4(sum.z, cnt.z, sum.w, cnt.w);
}

// ------- kernel 1.5: in-place exclusive prefix over segments (per n) -------
__global__ __launch_bounds__(256) void pme_prefix(
    float* __restrict__ part)       // (N, SEG, 256) x {sum, cnt}
{
    const int tid  = threadIdx.x;
    const int w    = tid >> 6;
    const int lane = tid & 63;
    const int n    = blockIdx.x * 4 + w;   // one wave per n

    float4* p = (float4*)part + (size_t)n * SEG * 128 + lane * 2;

    float4 ra = make_float4(0.f, 0.f, 0.f, 0.f);
    float4 rb = make_float4(0.f, 0.f, 0.f, 0.f);
    for (int s = 0; s < SEG; ++s) {
        float4 a = p[(size_t)s * 128];
        float4 b = p[(size_t)s * 128 + 1];
        p[(size_t)s * 128]     = ra;
        p[(size_t)s * 128 + 1] = rb;
        ra.x += a.x; ra.y += a.y; ra.z += a.z; ra.w += a.w;
        rb.x += b.x; rb.y += b.y; rb.z += b.z; rb.w += b.w;
    }
}

// ------------- kernel 2: scan + fused dem write (NT stores) -------------
__global__ __launch_bounds__(256) void pme_scan(
    const float* __restrict__ ts,   // (N, L, 256)
    const float* __restrict__ part, // (N, SEG, 256) x {sum, cnt} EXCLUSIVE prefixes
    const float* __restrict__ dem,  // (N, 10)
    const float* __restrict__ W1, const float* __restrict__ b1,
    const float* __restrict__ W2, const float* __restrict__ b2,
    float* __restrict__ out)        // (N, L, 276)
{
    const int tid  = threadIdx.x;
    const int w    = tid >> 6;
    const int lane = tid & 63;

    const int unit = blockIdx.x * 4 + w;
    const int seg  = unit & (SEG - 1);
    const int n    = unit >> 6;

    // ---- dem MLP (wave-uniform, redundant per wave; L1-broadcast loads) ----
    const float* dn = dem + n * DEMD;
    float h[H1];
#pragma unroll
    for (int k = 0; k < H1; ++k) {
        float hk = b1[k];
#pragma unroll
        for (int i = 0; i < DEMD; ++i)
            hk += dn[i] * W1[i * H1 + k];
        h[k] = fmaxf(hk, 0.f);
    }
    float4 e4q = make_float4(0.f, 0.f, 0.f, 0.f);
    {
        const int q = (lane < 5) ? lane : 0;
        float e0 = b2[q * 4 + 0], e1 = b2[q * 4 + 1], e2 = b2[q * 4 + 2], e3 = b2[q * 4 + 3];
#pragma unroll
        for (int k = 0; k < H1; ++k) {
            e0 += h[k] * W2[k * H2 + q * 4 + 0];
            e1 += h[k] * W2[k * H2 + q * 4 + 1];
            e2 += h[k] * W2[k * H2 + q * 4 + 2];
            e3 += h[k] * W2[k * H2 + q * 4 + 3];
        }
        e4q = make_float4(fmaxf(e0, 0.f), fmaxf(e1, 0.f), fmaxf(e2, 0.f), fmaxf(e3, 0.f));
    }

    // ---- exclusive prefix: single 32 B read ----
    const float4* pp = (const float4*)part + ((size_t)n * SEG + seg) * 128 + lane * 2;
    float4 a  = pp[0];
    float4 bq = pp[1];
    float4 acc = make_float4(a.x,  a.z,  bq.x, bq.z);
    float4 cnt = make_float4(a.y,  a.w,  bq.y, bq.w);

    const float4* tp = (const float4*)(ts + ((size_t)n * LL + seg * LSEG) * CIN) + lane;
    float* oprow = out + ((size_t)n * LL + seg * LSEG) * COUT;

    float4 v[2][UB];
#pragma unroll
    for (int u = 0; u < UB; ++u)
        v[0][u] = tp[(size_t)u * (CIN / 4)];

    for (int bb = 0; bb < NBATCH; ++bb) {
        const int cur = bb & 1;
        // prefetch next batch BEFORE this batch's stores
        if (bb + 1 < NBATCH) {
#pragma unroll
            for (int u = 0; u < UB; ++u)
                v[cur ^ 1][u] = tp[(size_t)((bb + 1) * UB + u) * (CIN / 4)];
        }
#pragma unroll
        for (int u = 0; u < UB; ++u) {
            float4 x = v[cur][u];
            float4 r;
            acc.x += x.x; cnt.x += (x.x != 0.f) ? 1.f : 0.f;
            acc.y += x.y; cnt.y += (x.y != 0.f) ? 1.f : 0.f;
            acc.z += x.z; cnt.z += (x.z != 0.f) ? 1.f : 0.f;
            acc.w += x.w; cnt.w += (x.w != 0.f) ? 1.f : 0.f;
            r.x = fmaxf(acc.x * __builtin_amdgcn_rcpf(fmaxf(cnt.x, 1.f)), 0.f);
            r.y = fmaxf(acc.y * __builtin_amdgcn_rcpf(fmaxf(cnt.y, 1.f)), 0.f);
            r.z = fmaxf(acc.z * __builtin_amdgcn_rcpf(fmaxf(cnt.z, 1.f)), 0.f);
            r.w = fmaxf(acc.w * __builtin_amdgcn_rcpf(fmaxf(cnt.w, 1.f)), 0.f);
            float* rowp = oprow + (size_t)(bb * UB + u) * COUT;
            nt_store4(rowp + lane * 4, r);            // channels 0..255, coalesced
            if (lane < 5)
                nt_store4(rowp + CIN + lane * 4, e4q); // channels 256..275
        }
    }
}

extern "C" void kernel_launch(void* const* d_in, const int* in_sizes, int n_in,
                              void* d_out, int out_size, void* d_ws, size_t ws_size,
                              hipStream_t stream) {
    const float* ts  = (const float*)d_in[0];
    const float* dem = (const float*)d_in[1];
    const float* W1  = (const float*)d_in[2];
    const float* b1  = (const float*)d_in[3];
    const float* W2  = (const float*)d_in[4];
    const float* b2  = (const float*)d_in[5];
    float* out  = (float*)d_out;
    float* part = (float*)d_ws;   // 64*64*256*2 floats = 8.4 MB

    pme_partials<<<(NB * SEG) / 4, 256, 0, stream>>>(ts, part);
    pme_prefix<<<NB / 4, 256, 0, stream>>>(part);
    pme_scan<<<(NB * SEG) / 4, 256, 0, stream>>>(ts, part, dem, W1, b1, W2, b2, out);
}